// Round 1
// baseline (217.136 us; speedup 1.0000x reference)
//
#include <hip/hip_runtime.h>
#include <stdint.h>

#define Bn 8
#define Nn 1024
#define Fn 64
#define Tn 32
#define Kn 3
#define On 64
#define Rn (Kn * Nn)   // 3072 reduction dim (k,j)
#define Cn (On * Tn)   // 2048 output cols (o,t)

typedef __bf16 bf16x8 __attribute__((ext_vector_type(8)));
typedef float f32x4 __attribute__((ext_vector_type(4)));
typedef __attribute__((address_space(1))) void gvoid;
typedef __attribute__((address_space(3))) void lvoid;

union BF8 { bf16x8 v; ushort s[8]; uint4 q; };

static __device__ __forceinline__ ushort f2bf(float f) {
  uint32_t u = __float_as_uint(f);
  return (ushort)((u + 0x7FFFu + ((u >> 16) & 1u)) >> 16);
}

// K0: ThetaT[k][o][f] = Theta[k][f][o], bf16
__global__ void k_thetaT(const float* __restrict__ Theta, ushort* __restrict__ ThT) {
  int idx = blockIdx.x * 256 + threadIdx.x;
  if (idx < Kn * On * Fn) {
    int k = idx / (On * Fn);
    int rem = idx % (On * Fn);
    int o = rem / Fn, f = rem % Fn;
    ThT[idx] = f2bf(Theta[(k * Fn + f) * On + o]);
  }
}

// K1: W_T[b][i][k*Nn + j] = cheb[k][j][i] * att[b][j][i], bf16 (32x32 LDS transpose)
__global__ __launch_bounds__(256) void k_prepW(const float* __restrict__ att,
                                               const float* __restrict__ cheb,
                                               ushort* __restrict__ Wt) {
  __shared__ float tile[32][33];
  int i0 = blockIdx.x * 32, j0 = blockIdx.y * 32, b = blockIdx.z;
  int tid = threadIdx.x;
  int ci = tid & 31, rj = tid >> 5;  // 8 rows per pass
  float av[4];
#pragma unroll
  for (int p = 0; p < 4; p++) {
    int j = j0 + rj + p * 8;
    av[p] = att[((size_t)b * Nn + j) * Nn + i0 + ci];
  }
  for (int k = 0; k < Kn; k++) {
#pragma unroll
    for (int p = 0; p < 4; p++) {
      int j = j0 + rj + p * 8;
      tile[rj + p * 8][ci] = av[p] * cheb[((size_t)k * Nn + j) * Nn + i0 + ci];
    }
    __syncthreads();
#pragma unroll
    for (int p = 0; p < 4; p++) {
      int i = i0 + rj + p * 8;  // ci now indexes j
      Wt[((size_t)b * Nn + i) * Rn + (size_t)k * Nn + j0 + ci] = f2bf(tile[ci][rj + p * 8]);
    }
    __syncthreads();
  }
}

// K2: Y_T[b][c][k*Nn + j] = sum_f ThetaT[k][o][f] * x[b][j][f][t],  c = o*Tn + t
// block: (jt, b), 512 thr = 8 waves, each wave owns 4 j's; MFMA 16x16x32 (M=o,N=t,K=f)
__global__ __launch_bounds__(512) void k_prepY(const float* __restrict__ x,
                                               const ushort* __restrict__ ThT,
                                               ushort* __restrict__ Yt) {
  __shared__ ushort ylds[1024 * 32];  // 64 KB: [c_local][j_slot]
  int jt = blockIdx.x, b = blockIdx.y;
  int j0 = jt * 32;
  int tid = threadIdx.x;
  int lane = tid & 63, w = tid >> 6;
  int l15 = lane & 15, l4 = lane >> 4;

  // preload B-frags (x) for this wave's 4 j's: b[e] = x[j][f = ks*32 + l4*8 + e][t = tf*16 + l15]
  BF8 bfr[4][2][2];
#pragma unroll
  for (int jj = 0; jj < 4; jj++) {
    const float* xp = x + ((size_t)b * Nn + (j0 + w * 4 + jj)) * (Fn * Tn);
#pragma unroll
    for (int ks = 0; ks < 2; ks++)
#pragma unroll
      for (int tf = 0; tf < 2; tf++) {
        int t = tf * 16 + l15;
        int fb = ks * 32 + l4 * 8;
#pragma unroll
        for (int e = 0; e < 8; e++)
          bfr[jj][ks][tf].s[e] = f2bf(xp[(fb + e) * Tn + t]);
      }
  }

  for (int k = 0; k < Kn; k++) {
    for (int h = 0; h < 2; h++) {  // o-half: o = h*32 + [0,32)
      BF8 afr[2][2];  // [o2][ks]: a[e] = ThetaT[k][o][ks*32 + l4*8 + e]
#pragma unroll
      for (int o2 = 0; o2 < 2; o2++)
#pragma unroll
        for (int ks = 0; ks < 2; ks++) {
          int o = h * 32 + o2 * 16 + l15;
          afr[o2][ks].q = *(const uint4*)&ThT[((size_t)k * On + o) * Fn + ks * 32 + l4 * 8];
        }
#pragma unroll
      for (int jj = 0; jj < 4; jj++) {
        f32x4 acc[2][2] = {};
#pragma unroll
        for (int ks = 0; ks < 2; ks++)
#pragma unroll
          for (int o2 = 0; o2 < 2; o2++)
#pragma unroll
            for (int tf = 0; tf < 2; tf++)
              acc[o2][tf] = __builtin_amdgcn_mfma_f32_16x16x32_bf16(
                  afr[o2][ks].v, bfr[jj][ks][tf].v, acc[o2][tf], 0, 0, 0);
        // D: row=o_local=(o2*16 + l4*4 + q), col=t=(tf*16 + l15)
#pragma unroll
        for (int o2 = 0; o2 < 2; o2++)
#pragma unroll
          for (int tf = 0; tf < 2; tf++)
#pragma unroll
            for (int q = 0; q < 4; q++) {
              int cl = (o2 * 16 + l4 * 4 + q) * Tn + tf * 16 + l15;
              ylds[cl * 32 + w * 4 + jj] = f2bf(acc[o2][tf][q]);
            }
      }
      __syncthreads();
      // cooperative write: 1024 rows (c = h*1024 + cl), 32 bf16 each (64B, full sector)
      const uint32_t* yl32 = (const uint32_t*)ylds;
      uint32_t* Yt32 = (uint32_t*)Yt;
      int e = tid & 15, rowst = tid >> 4;
      for (int pass = 0; pass < 32; pass++) {
        int cl = pass * 32 + rowst;
        size_t off = ((size_t)b * Cn + (size_t)(h * 1024 + cl)) * Rn + (size_t)k * Nn + j0;
        Yt32[off / 2 + e] = yl32[cl * 16 + e];
      }
      __syncthreads();
    }
  }
}

// K3: out[b][i][c] = relu( sum_r Wt[b][i][r] * Yt[b][c][r] )  — m97-style gemm_bt
__global__ __launch_bounds__(256) void k_gemm(const ushort* __restrict__ Wt,
                                              const ushort* __restrict__ Yt,
                                              float* __restrict__ out) {
  __shared__ ushort As[128 * 64];
  __shared__ ushort Bs[128 * 64];
  int b = blockIdx.z;
  int i0 = blockIdx.y * 128, c0 = blockIdx.x * 128;
  int tid = threadIdx.x, lane = tid & 63, w = tid >> 6;
  int l15 = lane & 15, l4 = lane >> 4;
  int wm = (w >> 1) * 64, wn = (w & 1) * 64;
  const ushort* Ab = Wt + (size_t)b * Nn * Rn + (size_t)i0 * Rn;
  const ushort* Bb = Yt + (size_t)b * Cn * Rn + (size_t)c0 * Rn;
  f32x4 acc[4][4] = {};
  int srow = lane >> 3, schunk = lane & 7;

  for (int kt = 0; kt < Rn / 64; kt++) {
#pragma unroll
    for (int cc = 0; cc < 4; cc++) {
      int rbase = (cc * 4 + w) * 8;
      const ushort* ga = Ab + (size_t)(rbase + srow) * Rn + kt * 64 + schunk * 8;
      const ushort* gb = Bb + (size_t)(rbase + srow) * Rn + kt * 64 + schunk * 8;
      __builtin_amdgcn_global_load_lds((gvoid*)ga, (lvoid*)(As + rbase * 64), 16, 0, 0);
      __builtin_amdgcn_global_load_lds((gvoid*)gb, (lvoid*)(Bs + rbase * 64), 16, 0, 0);
    }
    __syncthreads();
#pragma unroll
    for (int ks = 0; ks < 2; ks++) {
      BF8 af[4], bf[4];
#pragma unroll
      for (int m = 0; m < 4; m++)
        af[m].q = *(const uint4*)&As[(wm + m * 16 + l15) * 64 + ks * 32 + l4 * 8];
#pragma unroll
      for (int n = 0; n < 4; n++)
        bf[n].q = *(const uint4*)&Bs[(wn + n * 16 + l15) * 64 + ks * 32 + l4 * 8];
#pragma unroll
      for (int m = 0; m < 4; m++)
#pragma unroll
        for (int n = 0; n < 4; n++)
          acc[m][n] = __builtin_amdgcn_mfma_f32_16x16x32_bf16(af[m].v, bf[n].v, acc[m][n], 0, 0, 0);
    }
    __syncthreads();
  }

  float* ob = out + (size_t)b * Nn * Cn;
#pragma unroll
  for (int m = 0; m < 4; m++)
#pragma unroll
    for (int n = 0; n < 4; n++)
#pragma unroll
      for (int q = 0; q < 4; q++) {
        int i = i0 + wm + m * 16 + l4 * 4 + q;
        int c = c0 + wn + n * 16 + l15;
        ob[(size_t)i * Cn + c] = fmaxf(acc[m][n][q], 0.0f);
      }
}

extern "C" void kernel_launch(void* const* d_in, const int* in_sizes, int n_in,
                              void* d_out, int out_size, void* d_ws, size_t ws_size,
                              hipStream_t stream) {
  const float* x     = (const float*)d_in[0];  // (B,N,F,T)
  const float* att   = (const float*)d_in[1];  // (B,N,N)
  const float* cheb  = (const float*)d_in[2];  // (K,N,N)
  const float* Theta = (const float*)d_in[3];  // (K,F,O)
  float* out = (float*)d_out;                  // (B,N,O,T)

  char* ws = (char*)d_ws;
  ushort* ThT = (ushort*)ws;                              // 24 KB (padded region 64 KB)
  ushort* Wt  = (ushort*)(ws + 65536);                    // 8*1024*3072*2 = 50,331,648 B
  ushort* Yt  = (ushort*)(ws + 65536 + 50331648ull);      // 8*2048*3072*2 = 100,663,296 B

  k_thetaT<<<48, 256, 0, stream>>>(Theta, ThT);
  k_prepW<<<dim3(32, 32, 8), 256, 0, stream>>>(att, cheb, Wt);
  k_prepY<<<dim3(32, 8), 512, 0, stream>>>(x, ThT, Yt);
  k_gemm<<<dim3(16, 8, 8), 256, 0, stream>>>(Wt, Yt, out);
}

// Round 2
// 169.873 us; speedup vs baseline: 1.2782x; 1.2782x over previous
//
#include <hip/hip_runtime.h>
#include <stdint.h>

#define Bn 8
#define Nn 1024
#define Fn 64
#define Tn 32
#define Kn 3
#define On 64
#define Rn (Kn * Nn)   // 3072 reduction dim (k,j)
#define Cn (On * Tn)   // 2048 output cols (o,t)
#define NT (Rn / 32)   // 96 K-tiles of BK=32

typedef __bf16 bf16x8 __attribute__((ext_vector_type(8)));
typedef float f32x4 __attribute__((ext_vector_type(4)));
typedef __attribute__((address_space(1))) void gvoid;
typedef __attribute__((address_space(3))) void lvoid;

union BF8 { bf16x8 v; ushort s[8]; uint4 q; };

static __device__ __forceinline__ ushort f2bf(float f) {
  uint32_t u = __float_as_uint(f);
  return (ushort)((u + 0x7FFFu + ((u >> 16) & 1u)) >> 16);
}

static __device__ __forceinline__ void glds(const ushort* g, ushort* l) {
  __builtin_amdgcn_global_load_lds((gvoid*)g, (lvoid*)l, 16, 0, 0);
}

// K0: ThetaT[k][o][f] = Theta[k][f][o], bf16
__global__ void k_thetaT(const float* __restrict__ Theta, ushort* __restrict__ ThT) {
  int idx = blockIdx.x * 256 + threadIdx.x;
  if (idx < Kn * On * Fn) {
    int k = idx / (On * Fn);
    int rem = idx % (On * Fn);
    int o = rem / Fn, f = rem % Fn;
    ThT[idx] = f2bf(Theta[(k * Fn + f) * On + o]);
  }
}

// K1: W_T[b][i][k*Nn + j] = cheb[k][j][i] * att[b][j][i], bf16 (32x32 LDS transpose)
__global__ __launch_bounds__(256) void k_prepW(const float* __restrict__ att,
                                               const float* __restrict__ cheb,
                                               ushort* __restrict__ Wt) {
  __shared__ float tile[32][33];
  int i0 = blockIdx.x * 32, j0 = blockIdx.y * 32, b = blockIdx.z;
  int tid = threadIdx.x;
  int ci = tid & 31, rj = tid >> 5;  // 8 rows per pass
  float av[4];
#pragma unroll
  for (int p = 0; p < 4; p++) {
    int j = j0 + rj + p * 8;
    av[p] = att[((size_t)b * Nn + j) * Nn + i0 + ci];
  }
  for (int k = 0; k < Kn; k++) {
#pragma unroll
    for (int p = 0; p < 4; p++) {
      int j = j0 + rj + p * 8;
      tile[rj + p * 8][ci] = av[p] * cheb[((size_t)k * Nn + j) * Nn + i0 + ci];
    }
    __syncthreads();
#pragma unroll
    for (int p = 0; p < 4; p++) {
      int i = i0 + rj + p * 8;  // ci now indexes j
      Wt[((size_t)b * Nn + i) * Rn + (size_t)k * Nn + j0 + ci] = f2bf(tile[ci][rj + p * 8]);
    }
    __syncthreads();
  }
}

// K2: Y_T[b][c][k*Nn + j] = sum_f ThetaT[k][o][f] * x[b][j][f][t],  c = o*Tn + t
__global__ __launch_bounds__(512) void k_prepY(const float* __restrict__ x,
                                               const ushort* __restrict__ ThT,
                                               ushort* __restrict__ Yt) {
  __shared__ ushort ylds[1024 * 32];  // 64 KB: [c_local][j_slot]
  int jt = blockIdx.x, b = blockIdx.y;
  int j0 = jt * 32;
  int tid = threadIdx.x;
  int lane = tid & 63, w = tid >> 6;
  int l15 = lane & 15, l4 = lane >> 4;

  BF8 bfr[4][2][2];
#pragma unroll
  for (int jj = 0; jj < 4; jj++) {
    const float* xp = x + ((size_t)b * Nn + (j0 + w * 4 + jj)) * (Fn * Tn);
#pragma unroll
    for (int ks = 0; ks < 2; ks++)
#pragma unroll
      for (int tf = 0; tf < 2; tf++) {
        int t = tf * 16 + l15;
        int fb = ks * 32 + l4 * 8;
#pragma unroll
        for (int e = 0; e < 8; e++)
          bfr[jj][ks][tf].s[e] = f2bf(xp[(fb + e) * Tn + t]);
      }
  }

  for (int k = 0; k < Kn; k++) {
    for (int h = 0; h < 2; h++) {  // o-half
      BF8 afr[2][2];
#pragma unroll
      for (int o2 = 0; o2 < 2; o2++)
#pragma unroll
        for (int ks = 0; ks < 2; ks++) {
          int o = h * 32 + o2 * 16 + l15;
          afr[o2][ks].q = *(const uint4*)&ThT[((size_t)k * On + o) * Fn + ks * 32 + l4 * 8];
        }
#pragma unroll
      for (int jj = 0; jj < 4; jj++) {
        f32x4 acc[2][2] = {};
#pragma unroll
        for (int ks = 0; ks < 2; ks++)
#pragma unroll
          for (int o2 = 0; o2 < 2; o2++)
#pragma unroll
            for (int tf = 0; tf < 2; tf++)
              acc[o2][tf] = __builtin_amdgcn_mfma_f32_16x16x32_bf16(
                  afr[o2][ks].v, bfr[jj][ks][tf].v, acc[o2][tf], 0, 0, 0);
#pragma unroll
        for (int o2 = 0; o2 < 2; o2++)
#pragma unroll
          for (int tf = 0; tf < 2; tf++)
#pragma unroll
            for (int q = 0; q < 4; q++) {
              int cl = (o2 * 16 + l4 * 4 + q) * Tn + tf * 16 + l15;
              ylds[cl * 32 + w * 4 + jj] = f2bf(acc[o2][tf][q]);
            }
      }
      __syncthreads();
      const uint32_t* yl32 = (const uint32_t*)ylds;
      uint32_t* Yt32 = (uint32_t*)Yt;
      int e = tid & 15, rowst = tid >> 4;
      for (int pass = 0; pass < 32; pass++) {
        int cl = pass * 32 + rowst;
        size_t off = ((size_t)b * Cn + (size_t)(h * 1024 + cl)) * Rn + (size_t)k * Nn + j0;
        Yt32[off / 2 + e] = yl32[cl * 16 + e];
      }
      __syncthreads();
    }
  }
}

// K3: out[b][i][c] = relu( sum_r Wt[b][i][r] * Yt[b][c][r] )
// 256x256 tile, BK=32, 8 waves (2Mx4N), 4-deep LDS pipeline, counted vmcnt(8).
__global__ __launch_bounds__(512, 2) void k_gemm(const ushort* __restrict__ Wt,
                                                 const ushort* __restrict__ Yt,
                                                 float* __restrict__ out) {
  extern __shared__ __align__(16) ushort smem[];
  ushort* As = smem;           // 4 bufs x (256x32) = 32768 ushorts (64 KB)
  ushort* Bs = smem + 32768;   // 4 bufs x (256x32)

  int g = blockIdx.x;
  int b = g & 7, slot = g >> 3;          // each b's 32 tiles share one XCD (g%8 RR)
  int i0 = (slot & 3) * 256, c0 = (slot >> 2) * 256;
  int tid = threadIdx.x, lane = tid & 63, w = tid >> 6;
  int l15 = lane & 15, l4 = lane >> 4;
  int wm = w >> 2, wn = w & 3;

  const ushort* Ab = Wt + ((size_t)b * Nn + i0) * Rn;
  const ushort* Bb = Yt + ((size_t)b * Cn + c0) * Rn;

  // staging: thread covers 16B chunk L = tid (rows 0..127) and L+512 (rows 128..255)
  int srow = tid >> 2, sch = (tid & 3) * 8;
  const ushort* aS = Ab + (size_t)srow * Rn + sch;
  const ushort* bS = Bb + (size_t)srow * Rn + sch;
  int dst0 = w * 512;  // wave-uniform dest element offset within buf

  int abase = (wm * 128 + l15) * 32 + l4 * 8;  // element offset within buf
  int bbase = (wn * 64 + l15) * 32 + l4 * 8;

  f32x4 acc[8][4] = {};

#define STAGE_A(t) { int bo_ = ((t) & 3) * 8192; \
    glds(aS + (size_t)(t) * 32, As + bo_ + dst0); \
    glds(aS + 128 * (size_t)Rn + (size_t)(t) * 32, As + bo_ + 4096 + dst0); }
#define STAGE_B(t) { int bo_ = ((t) & 3) * 8192; \
    glds(bS + (size_t)(t) * 32, Bs + bo_ + dst0); \
    glds(bS + 128 * (size_t)Rn + (size_t)(t) * 32, Bs + bo_ + 4096 + dst0); }

  STAGE_A(0); STAGE_B(0);
  STAGE_A(1); STAGE_B(1);
  STAGE_A(2); STAGE_B(2);
  asm volatile("s_waitcnt vmcnt(8)" ::: "memory");  // K-tile 0 landed
  __builtin_amdgcn_s_barrier();

#define WINDOW(t, DOSTAGE) { \
    int bo_ = ((t) & 3) * 8192; \
    const ushort* Abuf = As + bo_; \
    const ushort* Bbuf = Bs + bo_; \
    BF8 bf[4], af[8]; \
    _Pragma("unroll") for (int n = 0; n < 4; n++) \
      bf[n].q = *(const uint4*)&Bbuf[bbase + n * 512]; \
    _Pragma("unroll") for (int m = 0; m < 4; m++) \
      af[m].q = *(const uint4*)&Abuf[abase + m * 512]; \
    if (DOSTAGE) STAGE_A((t) + 3); \
    __builtin_amdgcn_s_setprio(1); \
    _Pragma("unroll") for (int m = 0; m < 4; m++) \
      _Pragma("unroll") for (int n = 0; n < 4; n++) \
        acc[m][n] = __builtin_amdgcn_mfma_f32_16x16x32_bf16(af[m].v, bf[n].v, acc[m][n], 0, 0, 0); \
    __builtin_amdgcn_s_setprio(0); \
    _Pragma("unroll") for (int m = 4; m < 8; m++) \
      af[m].q = *(const uint4*)&Abuf[abase + m * 512]; \
    if (DOSTAGE) STAGE_B((t) + 3); \
    __builtin_amdgcn_s_setprio(1); \
    _Pragma("unroll") for (int m = 4; m < 8; m++) \
      _Pragma("unroll") for (int n = 0; n < 4; n++) \
        acc[m][n] = __builtin_amdgcn_mfma_f32_16x16x32_bf16(af[m].v, bf[n].v, acc[m][n], 0, 0, 0); \
    __builtin_amdgcn_s_setprio(0); \
  }

  for (int t = 0; t < NT - 3; ++t) {
    WINDOW(t, 1);
    // steady state: stages t+2 (4 loads) + t+3 (4 loads) stay in flight; t+1 landed
    asm volatile("s_waitcnt vmcnt(8)" ::: "memory");
    __builtin_amdgcn_s_barrier();
  }
  WINDOW(NT - 3, 0);
  asm volatile("s_waitcnt vmcnt(4)" ::: "memory");
  __builtin_amdgcn_s_barrier();
  WINDOW(NT - 2, 0);
  asm volatile("s_waitcnt vmcnt(0)" ::: "memory");
  __builtin_amdgcn_s_barrier();
  WINDOW(NT - 1, 0);

#undef WINDOW
#undef STAGE_A
#undef STAGE_B

  float* ob = out + (size_t)b * Nn * Cn;
#pragma unroll
  for (int m = 0; m < 8; m++) {
    int i = i0 + wm * 128 + m * 16 + l4 * 4;
#pragma unroll
    for (int n = 0; n < 4; n++) {
      int c = c0 + wn * 64 + n * 16 + l15;
#pragma unroll
      for (int q = 0; q < 4; q++)
        ob[(size_t)(i + q) * Cn + c] = fmaxf(acc[m][n][q], 0.0f);
    }
  }
}

extern "C" void kernel_launch(void* const* d_in, const int* in_sizes, int n_in,
                              void* d_out, int out_size, void* d_ws, size_t ws_size,
                              hipStream_t stream) {
  const float* x     = (const float*)d_in[0];  // (B,N,F,T)
  const float* att   = (const float*)d_in[1];  // (B,N,N)
  const float* cheb  = (const float*)d_in[2];  // (K,N,N)
  const float* Theta = (const float*)d_in[3];  // (K,F,O)
  float* out = (float*)d_out;                  // (B,N,O,T)

  char* ws = (char*)d_ws;
  ushort* ThT = (ushort*)ws;                              // 24 KB (padded to 64 KB)
  ushort* Wt  = (ushort*)(ws + 65536);                    // 8*1024*3072*2 = 50,331,648 B
  ushort* Yt  = (ushort*)(ws + 65536 + 50331648ull);      // 8*2048*3072*2 = 100,663,296 B

  hipFuncSetAttribute((const void*)k_gemm, hipFuncAttributeMaxDynamicSharedMemorySize, 131072);

  k_thetaT<<<48, 256, 0, stream>>>(Theta, ThT);
  k_prepW<<<dim3(32, 32, 8), 256, 0, stream>>>(att, cheb, Wt);
  k_prepY<<<dim3(32, 8), 512, 0, stream>>>(x, ThT, Yt);
  k_gemm<<<256, 512, 131072, stream>>>(Wt, Yt, out);
}